// Round 10
// baseline (114.764 us; speedup 1.0000x reference)
//
#include <hip/hip_runtime.h>
#include <math.h>

#define DIM 256
#define TM 256          // block tile rows (cond)
#define TN 128          // block tile cols (sol)
#define BK 64

typedef float f32x4 __attribute__((ext_vector_type(4)));
typedef long long2v __attribute__((ext_vector_type(2)));

typedef const __attribute__((address_space(1))) void* gas_ptr;
typedef __attribute__((address_space(3))) void* las_ptr;

__device__ __forceinline__ void async_cp16(const void* g, void* l) {
    __builtin_amdgcn_global_load_lds((gas_ptr)g, (las_ptr)l, 16, 0, 0);
}

// ---------------------------------------------------------------------------
// Kernel 1: fp32 -> fp8 e4m3 (HW cvt, same format MFMA consumes) in
// FRAGMENT-MAJOR order + exact fp32 row norms + exact fp32 diag cross-dots
// + zero-init of rowsum/colsum and out[0]. (R9-verified, unchanged.)
// ---------------------------------------------------------------------------
__global__ __launch_bounds__(256) void convert_kernel(
        const float* __restrict__ C, const float* __restrict__ S,
        unsigned char* __restrict__ Cb, unsigned char* __restrict__ Sb,
        float* __restrict__ c2, float* __restrict__ s2,
        float* __restrict__ ddot, float* __restrict__ sums0,
        float* __restrict__ out, int N) {
    int gtid = blockIdx.x * 256 + threadIdx.x;
    if (gtid < 2 * N) sums0[gtid] = 0.0f;
    if (gtid == 0) out[0] = 0.0f;
    int row = gtid >> 6;
    int l = gtid & 63;
    if (row >= N) return;
    float4 v  = ((const float4*)(C + (size_t)row * DIM))[l];
    float4 sv = ((const float4*)(S + (size_t)row * DIM))[l];
    int pc = __builtin_amdgcn_cvt_pk_fp8_f32(v.x, v.y, 0, false);
    pc     = __builtin_amdgcn_cvt_pk_fp8_f32(v.z, v.w, pc, true);
    int ps = __builtin_amdgcn_cvt_pk_fp8_f32(sv.x, sv.y, 0, false);
    ps     = __builtin_amdgcn_cvt_pk_fp8_f32(sv.z, sv.w, ps, true);
    // frag-major 4B index within the row
    int idx4 = (l >> 4) * 16 + ((l & 7) >> 1) * 4 + ((l & 15) >> 3) * 2 + (l & 1);
    ((int*)(Cb + (size_t)row * DIM))[idx4] = pc;
    ((int*)(Sb + (size_t)row * DIM))[idx4] = ps;
    float nc = v.x * v.x + v.y * v.y + v.z * v.z + v.w * v.w;
    float ns = sv.x * sv.x + sv.y * sv.y + sv.z * sv.z + sv.w * sv.w;
    float cr = v.x * sv.x + v.y * sv.y + v.z * sv.z + v.w * sv.w;
    #pragma unroll
    for (int off = 32; off > 0; off >>= 1) {
        nc += __shfl_down(nc, off, 64);
        ns += __shfl_down(ns, off, 64);
        cr += __shfl_down(cr, off, 64);
    }
    if (l == 0) { c2[row] = nc; s2[row] = ns; ddot[row] = cr; }
}

// ---------------------------------------------------------------------------
// Kernel 2: fp8 MFMA GEMM, 256x128 block tile, 8 waves of 64x64 wave tiles,
// DOUBLE-BUFFERED K-loop: prefetch group k+1 AFTER the barrier, compute
// group k, one barrier/iter. __syncthreads' forced vmcnt(0) then drains a
// prefetch that had the whole compute phase in flight (R9 exposed full L2
// latency 4x/block by staging immediately before the drain). Last iter has
// no barrier (no buffer reuse after). LDS swizzle: pchunk = chunk^(row&3);
// one ds_read_b128 per (row, 64B K-group) = both K=32 MFMA halves.
// Epilogue: norms pre-scaled by K2=(e^T*log2e)^2 -> add+fma+max+sqrt+exp2;
// split-exchange fold + LDS/global atomics. No device-scope fences.
// ---------------------------------------------------------------------------
__global__ __launch_bounds__(512, 4) void mfma_kernel(
        const unsigned char* __restrict__ Cb, const unsigned char* __restrict__ Sb,
        const float* __restrict__ c2, const float* __restrict__ s2,
        const float* __restrict__ temp,
        float* __restrict__ rowsum, float* __restrict__ colsum, int N) {
    __shared__ __align__(16) unsigned char Abuf[2][TM * BK];   // 32 KB
    __shared__ __align__(16) unsigned char Bbuf[2][TN * BK];   // 16 KB
    __shared__ float rs[TM], cs[TN], c2t[TM], s2t[TN];         // 3 KB

    const int tid = threadIdx.x;
    const int bm = blockIdx.y * TM;
    const int bn = blockIdx.x * TN;
    const int w  = tid >> 6;        // 0..7
    const int l  = tid & 63;
    const int wm = (w >> 1) * 64;   // 0,64,128,192
    const int wn = (w & 1) * 64;    // 0,64

    const float escale = __expf(temp[0]);
    const float Kf = escale * 1.4426950408889634f;   // e^T * log2(e)
    const float K2 = Kf * Kf;
    const float m2K2 = -2.0f * K2;

    if (tid < TM) { rs[tid] = 0.0f; c2t[tid] = K2 * c2[bm + tid]; }
    else if (tid < TM + TN) {
        int t = tid - TM; cs[t] = 0.0f; s2t[t] = K2 * s2[bn + t];
    }

    // --- staging: slot s = i*512 + w*64 + l <-> (row = s>>2, pchunk = s&3)
    // row = i*128 + w*16 + (l>>2); pchunk = l&3; row&3 == (l>>2)&3.
    const int l4 = l >> 2;
    const int sc = (l & 3) ^ (l4 & 3);   // source logical chunk
    const unsigned char* gA = Cb + (size_t)(bm + w * 16 + l4) * DIM + sc * 16;
    const unsigned char* gB = Sb + (size_t)(bn + w * 16 + l4) * DIM + sc * 16;
    const int lofs = w * 1024;           // wave-uniform LDS base offset
    const size_t askip = (size_t)128 * DIM;   // +128 rows for A instr i=1

    // --- fragment offsets (bytes): logical chunk q at row -> phys q^(row&3)
    const int m16 = l & 15;
    const int q = l >> 4;
    int aoff[4], boff[4];
    #pragma unroll
    for (int i = 0; i < 4; ++i) {
        aoff[i] = (wm + i * 16 + m16) * BK + ((q ^ (m16 & 3)) * 16);
        boff[i] = (wn + i * 16 + m16) * BK + ((q ^ (m16 & 3)) * 16);
    }

    f32x4 acc[4][4] = {};

    // prologue: stage group 0 into buffer 0 (latency exposed once)
    async_cp16(gA,         &Abuf[0][lofs]);
    async_cp16(gA + askip, &Abuf[0][lofs + 8192]);
    async_cp16(gB,         &Bbuf[0][lofs]);
    gA += BK; gB += BK;
    __syncthreads();

    #pragma unroll
    for (int kk = 0; kk < 4; ++kk) {
        const int cur = kk & 1;
        if (kk < 3) {   // prefetch next group into the other buffer
            async_cp16(gA,         &Abuf[cur ^ 1][lofs]);
            async_cp16(gA + askip, &Abuf[cur ^ 1][lofs + 8192]);
            async_cp16(gB,         &Bbuf[cur ^ 1][lofs]);
            gA += BK; gB += BK;
        }
        long2v af[4], bf[4];
        #pragma unroll
        for (int i = 0; i < 4; ++i) af[i] = *(const long2v*)&Abuf[cur][aoff[i]];
        #pragma unroll
        for (int j = 0; j < 4; ++j) bf[j] = *(const long2v*)&Bbuf[cur][boff[j]];
        #pragma unroll
        for (int mi = 0; mi < 4; ++mi)
            #pragma unroll
            for (int ni = 0; ni < 4; ++ni) {
                acc[mi][ni] = __builtin_amdgcn_mfma_f32_16x16x32_fp8_fp8(
                    af[mi].x, bf[ni].x, acc[mi][ni], 0, 0, 0);
                acc[mi][ni] = __builtin_amdgcn_mfma_f32_16x16x32_fp8_fp8(
                    af[mi].y, bf[ni].y, acc[mi][ni], 0, 0, 0);
            }
        if (kk < 3) __syncthreads();   // drains prefetch (hidden by compute)
    }

    // --- fused epilogue; C/D layout (m89): col = lane&15, row = q*4 + reg.
    float c2v[4][4], s2v[4];
    #pragma unroll
    for (int mi = 0; mi < 4; ++mi)
        #pragma unroll
        for (int r = 0; r < 4; ++r) c2v[mi][r] = c2t[wm + mi * 16 + q * 4 + r];
    #pragma unroll
    for (int ni = 0; ni < 4; ++ni) s2v[ni] = s2t[wn + ni * 16 + m16];

    float rp[16];   // slot s = mi*4 + r
    #pragma unroll
    for (int s = 0; s < 16; ++s) rp[s] = 0.0f;
    float cp[4] = {0.f, 0.f, 0.f, 0.f};

    #pragma unroll
    for (int mi = 0; mi < 4; ++mi) {
        #pragma unroll
        for (int ni = 0; ni < 4; ++ni) {
            #pragma unroll
            for (int r = 0; r < 4; ++r) {
                // exp2(-sqrt(K2*d2)) == exp(-escale*dist)
                float d2 = fmaf(m2K2, acc[mi][ni][r], c2v[mi][r] + s2v[ni]);
                d2 = fmaxf(d2, 0.0f);
                float e = __builtin_amdgcn_exp2f(-__builtin_amdgcn_sqrtf(d2));
                rp[mi * 4 + r] += e;
                cp[ni] += e;
            }
        }
    }

    // --- split-exchange fold over the 16 lanes sharing q (R7-verified)
    #pragma unroll
    for (int b = 0; b < 4; ++b) {
        const int n = 16 >> b;
        const int bit = (m16 >> b) & 1;
        #pragma unroll
        for (int k = 0; k < 8; ++k) {
            if (k < (n >> 1)) {
                float keep = bit ? rp[2 * k + 1] : rp[2 * k];
                float send = bit ? rp[2 * k] : rp[2 * k + 1];
                float recv = __shfl_xor(send, 1 << b, 64);
                rp[k] = keep + recv;
            }
        }
    }
    const int myrow = wm + (m16 >> 2) * 16 + q * 4 + (m16 & 3);
    atomicAdd(&rs[myrow], rp[0]);   // 2-way collision (wn pair) only

    #pragma unroll
    for (int b = 0; b < 2; ++b) {
        const int n = 4 >> b;
        const int bit = (q >> b) & 1;
        #pragma unroll
        for (int k = 0; k < 2; ++k) {
            if (k < (n >> 1)) {
                float keep = bit ? cp[2 * k + 1] : cp[2 * k];
                float send = bit ? cp[2 * k] : cp[2 * k + 1];
                float recv = __shfl_xor(send, 16 << b, 64);
                cp[k] = keep + recv;
            }
        }
    }
    const int mycol = wn + q * 16 + m16;
    atomicAdd(&cs[mycol], cp[0]);   // 4-way collision (wm group)

    __syncthreads();
    if (tid < TM) atomicAdd(&rowsum[bm + tid], rs[tid]);
    else if (tid < TM + TN) atomicAdd(&colsum[bn + tid - TM], cs[tid - TM]);
}

// ---------------------------------------------------------------------------
// Kernel 3: finalize, 32 blocks, atomicAdd into out[0] (zeroed by kernel 1).
// diag dist reconstructed exactly from c2/s2/ddot (fp32).
// loss = (1/2N) * sum_i [log(rowsum_i) + log(colsum_i) + 2*e^T*dist_i]
// ---------------------------------------------------------------------------
__global__ __launch_bounds__(256) void finalize_kernel(
        const float* __restrict__ rowsum, const float* __restrict__ colsum,
        const float* __restrict__ c2, const float* __restrict__ s2,
        const float* __restrict__ ddot, const float* __restrict__ temp,
        float* __restrict__ out, int N) {
    __shared__ float red[4];
    const float escale = __expf(temp[0]);
    const int tid = threadIdx.x;
    int i = blockIdx.x * 256 + tid;
    float sum = 0.0f;
    if (i < N) {
        float d2 = c2[i] + s2[i] - 2.0f * ddot[i];
        float dist = __builtin_amdgcn_sqrtf(fmaxf(d2, 0.0f));
        sum = __logf(rowsum[i]) + __logf(colsum[i]) + 2.0f * escale * dist;
    }
    #pragma unroll
    for (int off = 32; off > 0; off >>= 1) sum += __shfl_down(sum, off, 64);
    if ((tid & 63) == 0) red[tid >> 6] = sum;
    __syncthreads();
    if (tid == 0)
        atomicAdd(out, (red[0] + red[1] + red[2] + red[3]) / (2.0f * (float)N));
}

extern "C" void kernel_launch(void* const* d_in, const int* in_sizes, int n_in,
                              void* d_out, int out_size, void* d_ws, size_t ws_size,
                              hipStream_t stream) {
    const float* C = (const float*)d_in[0];
    const float* S = (const float*)d_in[1];
    const float* T = (const float*)d_in[2];
    const int N = in_sizes[0] / DIM;   // 8192

    float* ws     = (float*)d_ws;
    float* c2     = ws;
    float* s2     = ws + N;
    float* rowsum = ws + 2 * N;
    float* colsum = ws + 3 * N;
    float* ddot   = ws + 4 * N;
    unsigned char* Cb = (unsigned char*)(ws + 5 * N + 64);  // 16B-aligned
    unsigned char* Sb = Cb + (size_t)N * DIM;

    convert_kernel<<<(N * 64) / 256, 256, 0, stream>>>(
        C, S, Cb, Sb, c2, s2, ddot, rowsum, (float*)d_out, N);

    dim3 grid(N / TN, N / TM);
    mfma_kernel<<<grid, 512, 0, stream>>>(
        Cb, Sb, c2, s2, T, rowsum, colsum, N);

    finalize_kernel<<<(N + 255) / 256, 256, 0, stream>>>(
        rowsum, colsum, c2, s2, ddot, T, (float*)d_out, N);
}

// Round 11
// 113.356 us; speedup vs baseline: 1.0124x; 1.0124x over previous
//
#include <hip/hip_runtime.h>
#include <math.h>

#define DIM 256
#define TM 256          // block tile rows (cond)
#define TN 128          // block tile cols (sol)
// K handled as 4 groups of 64 (one mfma_scale K-step each)

typedef int   v4i   __attribute__((ext_vector_type(4)));
typedef int   v8i   __attribute__((ext_vector_type(8)));
typedef float f32x16 __attribute__((ext_vector_type(16)));

typedef const __attribute__((address_space(1))) void* gas_ptr;
typedef __attribute__((address_space(3))) void* las_ptr;

__device__ __forceinline__ void async_cp16(const void* g, void* l) {
    __builtin_amdgcn_global_load_lds((gas_ptr)g, (las_ptr)l, 16, 0, 0);
}

// ---------------------------------------------------------------------------
// Kernel 1: fp32 -> fp8 e4m3 in OPERAND-MAJOR order + exact fp32 row norms +
// exact fp32 diag cross-dots + zero-init of rowsum/colsum and out[0].
// Operand-major: data is laid out exactly as mfma_scale_32x32x64 wants it in
// LDS: per (32-row group, 64-K group) "tile" of 2048 B, byte (row, k_local)
// sits at  i*1024 + lane*16 + j  with lane = (row&31)+32*(k_local>>5),
// i = (k_local>>4)&1, j = k_local&15.  GEMM staging then is a SEQUENTIAL
// copy (cp16 src/dst = base + l*16) and fragment reads are two fully
// sequential ds_read_b128 per tile (conflict-free by construction).
// ---------------------------------------------------------------------------
__global__ __launch_bounds__(256) void convert_kernel(
        const float* __restrict__ C, const float* __restrict__ S,
        unsigned char* __restrict__ Cb, unsigned char* __restrict__ Sb,
        float* __restrict__ c2, float* __restrict__ s2,
        float* __restrict__ ddot, float* __restrict__ sums0,
        float* __restrict__ out, int N) {
    int gtid = blockIdx.x * 256 + threadIdx.x;
    if (gtid < 2 * N) sums0[gtid] = 0.0f;
    if (gtid == 0) out[0] = 0.0f;
    int row = gtid >> 6;
    int l = gtid & 63;
    if (row >= N) return;
    float4 v  = ((const float4*)(C + (size_t)row * DIM))[l];
    float4 sv = ((const float4*)(S + (size_t)row * DIM))[l];
    int pc = __builtin_amdgcn_cvt_pk_fp8_f32(v.x, v.y, 0, false);
    pc     = __builtin_amdgcn_cvt_pk_fp8_f32(v.z, v.w, pc, true);
    int ps = __builtin_amdgcn_cvt_pk_fp8_f32(sv.x, sv.y, 0, false);
    ps     = __builtin_amdgcn_cvt_pk_fp8_f32(sv.z, sv.w, ps, true);
    // lane l holds bytes k = 4l..4l+3: g=l>>4, khalf=(l>>3)&1, i=(l>>2)&1,
    // dword j4 = l&3. int index within the whole buffer:
    int idx4 = (row >> 5) * 2048 + (l >> 4) * 512 + ((l >> 2) & 1) * 256
             + ((row & 31) + 32 * ((l >> 3) & 1)) * 4 + (l & 3);
    ((int*)Cb)[idx4] = pc;
    ((int*)Sb)[idx4] = ps;
    float nc = v.x * v.x + v.y * v.y + v.z * v.z + v.w * v.w;
    float ns = sv.x * sv.x + sv.y * sv.y + sv.z * sv.z + sv.w * sv.w;
    float cr = v.x * sv.x + v.y * sv.y + v.z * sv.z + v.w * sv.w;
    #pragma unroll
    for (int off = 32; off > 0; off >>= 1) {
        nc += __shfl_down(nc, off, 64);
        ns += __shfl_down(ns, off, 64);
        cr += __shfl_down(cr, off, 64);
    }
    if (l == 0) { c2[row] = nc; s2[row] = ns; ddot[row] = cr; }
}

// ---------------------------------------------------------------------------
// Kernel 2: MX-scaled fp8 GEMM (mfma_scale_f32_32x32x64_f8f6f4, scale=1.0):
// 2x the fp8 MFMA rate and 8x fewer MFMA instructions than R9's 16x16x32.
// 256x128 block tile, 8 waves of 64x64 wave tiles (2x2 frags of 32x32).
// Single-buffered K-loop (R10 dbuf was neutral/regressive). Operand-major
// LDS: staging = sequential copy, frags = sequential b128 pairs.
// Epilogue: norms pre-scaled by K2=(e^T*log2e)^2 -> add+fma+max+sqrt+exp2;
// zero-redundancy fold: 64 rows/cols of the wave tile end on 64 lanes.
// C/D layout 32x32 (m74/m101): col = lane&31, row = (s&3)+8*(s>>2)+4*(l>>5).
// ---------------------------------------------------------------------------
__global__ __launch_bounds__(512, 4) void mfma_kernel(
        const unsigned char* __restrict__ Cb, const unsigned char* __restrict__ Sb,
        const float* __restrict__ c2, const float* __restrict__ s2,
        const float* __restrict__ temp,
        float* __restrict__ rowsum, float* __restrict__ colsum, int N) {
    __shared__ __align__(16) unsigned char Abuf[TM * 64];   // 16 KB (8 tiles)
    __shared__ __align__(16) unsigned char Bbuf[TN * 64];   // 8 KB (4 tiles)
    __shared__ float rs[TM], cs[TN], c2t[TM], s2t[TN];      // 3 KB

    const int tid = threadIdx.x;
    const int bm = blockIdx.y * TM;
    const int bn = blockIdx.x * TN;
    const int w  = tid >> 6;        // 0..7
    const int l  = tid & 63;
    const int wm = (w >> 1) * 64;   // 0,64,128,192
    const int wn = (w & 1) * 64;    // 0,64

    const float escale = __expf(temp[0]);
    const float Kf = escale * 1.4426950408889634f;   // e^T * log2(e)
    const float K2 = Kf * Kf;
    const float m2K2 = -2.0f * K2;

    if (tid < TM) { rs[tid] = 0.0f; c2t[tid] = K2 * c2[bm + tid]; }
    else if (tid < TM + TN) {
        int t = tid - TM; cs[t] = 0.0f; s2t[t] = K2 * s2[bn + t];
    }

    // --- staging (operand-major => sequential): wave w copies A-tile w
    // (2 cp16) and half of a B-tile (1 cp16) per K-group.
    const unsigned char* gA = Cb + (size_t)((bm >> 5) + w) * 8192 + (size_t)l * 16;
    const unsigned char* gB = Sb + (size_t)((bn >> 5) + (w >> 1)) * 8192
                                 + (size_t)(w & 1) * 1024 + (size_t)l * 16;
    unsigned char* lA = &Abuf[w * 2048];
    unsigned char* lB = &Bbuf[(w >> 1) * 2048 + (w & 1) * 1024];

    // --- fragment bases: lane l's 32 K-bytes of tile t are at
    // [t*2048 + l*16, +16) and [t*2048 + 1024 + l*16, +16).
    const int abase = (w >> 1) * 4096 + l * 16;   // A-tiles (w>>1)*2, +1
    const int bbase = (w & 1) * 4096 + l * 16;    // B-tiles (w&1)*2, +1

    f32x16 acc[2][2] = {};

    #pragma unroll
    for (int kk = 0; kk < 4; ++kk) {
        async_cp16(gA, lA);
        async_cp16(gA + 1024, lA + 1024);
        async_cp16(gB, lB);
        gA += 2048; gB += 2048;
        __syncthreads();   // staging complete (vmcnt drain)

        v8i af[2], bf[2];
        #pragma unroll
        for (int t = 0; t < 2; ++t) {
            v4i alo = *(const v4i*)&Abuf[abase + t * 2048];
            v4i ahi = *(const v4i*)&Abuf[abase + t * 2048 + 1024];
            af[t] = __builtin_shufflevector(alo, ahi, 0, 1, 2, 3, 4, 5, 6, 7);
            v4i blo = *(const v4i*)&Bbuf[bbase + t * 2048];
            v4i bhi = *(const v4i*)&Bbuf[bbase + t * 2048 + 1024];
            bf[t] = __builtin_shufflevector(blo, bhi, 0, 1, 2, 3, 4, 5, 6, 7);
        }
        #pragma unroll
        for (int mi = 0; mi < 2; ++mi)
            #pragma unroll
            for (int ni = 0; ni < 2; ++ni)
                acc[mi][ni] = __builtin_amdgcn_mfma_scale_f32_32x32x64_f8f6f4(
                    af[mi], bf[ni], acc[mi][ni], 0, 0,   // fmt: fp8 e4m3 / e4m3
                    0, 0x7F, 0, 0x7F);                   // scales = 2^0 = 1.0
        __syncthreads();   // LDS consumed
    }

    // --- fused epilogue ---
    const int q2 = l >> 5;          // which row-quad offset (+4*q2)
    const int col5 = l & 31;
    float s2v[2] = { s2t[wn + col5], s2t[wn + 32 + col5] };

    float rfold[2];
    float cp[2] = {0.f, 0.f};

    #pragma unroll
    for (int mi = 0; mi < 2; ++mi) {
        float c2r[16];
        #pragma unroll
        for (int s = 0; s < 16; ++s)
            c2r[s] = c2t[wm + mi * 32 + (s & 3) + 8 * (s >> 2) + 4 * q2];
        float rp[16];
        #pragma unroll
        for (int s = 0; s < 16; ++s) rp[s] = 0.0f;
        #pragma unroll
        for (int ni = 0; ni < 2; ++ni) {
            #pragma unroll
            for (int s = 0; s < 16; ++s) {
                // exp2(-sqrt(K2*d2)) == exp(-escale*dist)
                float d2 = fmaf(m2K2, acc[mi][ni][s], c2r[s] + s2v[ni]);
                d2 = fmaxf(d2, 0.0f);
                float e = __builtin_amdgcn_exp2f(-__builtin_amdgcn_sqrtf(d2));
                rp[s] += e;
                cp[ni] += e;
            }
        }
        // 4-stage split-exchange fold (slots 16 -> 1 over masks 1,2,4,8)
        #pragma unroll
        for (int b = 0; b < 4; ++b) {
            const int n = 16 >> b;
            const int bit = (l >> b) & 1;
            #pragma unroll
            for (int k = 0; k < 8; ++k) {
                if (k < (n >> 1)) {
                    float keep = bit ? rp[2 * k + 1] : rp[2 * k];
                    float send = bit ? rp[2 * k] : rp[2 * k + 1];
                    rp[k] = keep + __shfl_xor(send, 1 << b, 64);
                }
            }
        }
        rfold[mi] = rp[0];
    }
    // stage 5: fold lanes l <-> l^16 while splitting mi (keeps own mi)
    const int mymi = (l >> 4) & 1;
    {
        float keep = mymi ? rfold[1] : rfold[0];
        float send = mymi ? rfold[0] : rfold[1];
        float rfin = keep + __shfl_xor(send, 16, 64);
        const int s = l & 15;
        const int myrow = wm + mymi * 32 + (s & 3) + 8 * (s >> 2) + 4 * q2;
        atomicAdd(&rs[myrow], rfin);   // 2-way collision (wn pair) only
    }
    // cols: fold lanes l <-> l^32 while splitting ni (keeps ni = q2)
    {
        float keep = q2 ? cp[1] : cp[0];
        float send = q2 ? cp[0] : cp[1];
        float cfin = keep + __shfl_xor(send, 32, 64);
        atomicAdd(&cs[wn + q2 * 32 + col5], cfin);   // 4-way (wm group)
    }

    __syncthreads();
    if (tid < TM) atomicAdd(&rowsum[bm + tid], rs[tid]);
    else if (tid < TM + TN) atomicAdd(&colsum[bn + tid - TM], cs[tid - TM]);
}

// ---------------------------------------------------------------------------
// Kernel 3: finalize, 32 blocks, atomicAdd into out[0] (zeroed by kernel 1).
// diag dist reconstructed exactly from c2/s2/ddot (fp32).
// loss = (1/2N) * sum_i [log(rowsum_i) + log(colsum_i) + 2*e^T*dist_i]
// ---------------------------------------------------------------------------
__global__ __launch_bounds__(256) void finalize_kernel(
        const float* __restrict__ rowsum, const float* __restrict__ colsum,
        const float* __restrict__ c2, const float* __restrict__ s2,
        const float* __restrict__ ddot, const float* __restrict__ temp,
        float* __restrict__ out, int N) {
    __shared__ float red[4];
    const float escale = __expf(temp[0]);
    const int tid = threadIdx.x;
    int i = blockIdx.x * 256 + tid;
    float sum = 0.0f;
    if (i < N) {
        float d2 = c2[i] + s2[i] - 2.0f * ddot[i];
        float dist = __builtin_amdgcn_sqrtf(fmaxf(d2, 0.0f));
        sum = __logf(rowsum[i]) + __logf(colsum[i]) + 2.0f * escale * dist;
    }
    #pragma unroll
    for (int off = 32; off > 0; off >>= 1) sum += __shfl_down(sum, off, 64);
    if ((tid & 63) == 0) red[tid >> 6] = sum;
    __syncthreads();
    if (tid == 0)
        atomicAdd(out, (red[0] + red[1] + red[2] + red[3]) / (2.0f * (float)N));
}

extern "C" void kernel_launch(void* const* d_in, const int* in_sizes, int n_in,
                              void* d_out, int out_size, void* d_ws, size_t ws_size,
                              hipStream_t stream) {
    const float* C = (const float*)d_in[0];
    const float* S = (const float*)d_in[1];
    const float* T = (const float*)d_in[2];
    const int N = in_sizes[0] / DIM;   // 8192

    float* ws     = (float*)d_ws;
    float* c2     = ws;
    float* s2     = ws + N;
    float* rowsum = ws + 2 * N;
    float* colsum = ws + 3 * N;
    float* ddot   = ws + 4 * N;
    unsigned char* Cb = (unsigned char*)(ws + 5 * N + 64);  // 16B-aligned
    unsigned char* Sb = Cb + (size_t)N * DIM;

    convert_kernel<<<(N * 64) / 256, 256, 0, stream>>>(
        C, S, Cb, Sb, c2, s2, ddot, rowsum, (float*)d_out, N);

    dim3 grid(N / TN, N / TM);
    mfma_kernel<<<grid, 512, 0, stream>>>(
        Cb, Sb, c2, s2, T, rowsum, colsum, N);

    finalize_kernel<<<(N + 255) / 256, 256, 0, stream>>>(
        rowsum, colsum, c2, s2, ddot, T, (float*)d_out, N);
}

// Round 12
// 105.635 us; speedup vs baseline: 1.0864x; 1.0731x over previous
//
#include <hip/hip_runtime.h>
#include <math.h>

#define DIM 256
#define TM 128          // block tile rows (cond)
#define TN 128          // block tile cols (sol)

typedef int   v4i    __attribute__((ext_vector_type(4)));
typedef int   v8i    __attribute__((ext_vector_type(8)));
typedef float f32x16 __attribute__((ext_vector_type(16)));

// ---------------------------------------------------------------------------
// Kernel 1: fp32 -> fp8 e4m3 in OPERAND-MAJOR order + exact fp32 row norms +
// exact fp32 diag cross-dots + zero-init of rowsum/colsum and out[0].
// Operand-major (R11-verified): per (32-row group, 64-K group) 2048-B tile,
// byte (row, k) sits at i*1024 + lane*16 + j with lane=(row&31)+32*(k>>5&1),
// i=(k>>4)&1, j=k&15. A wave's mfma_scale_32x32x64 fragment is then the
// CONTIGUOUS 16 B at tile_base + lane*16 (+1024 for the upper half) -- i.e.
// directly loadable from global with one coalesced dwordx4. No LDS needed.
// ---------------------------------------------------------------------------
__global__ __launch_bounds__(256) void convert_kernel(
        const float* __restrict__ C, const float* __restrict__ S,
        unsigned char* __restrict__ Cb, unsigned char* __restrict__ Sb,
        float* __restrict__ c2, float* __restrict__ s2,
        float* __restrict__ ddot, float* __restrict__ sums0,
        float* __restrict__ out, int N) {
    int gtid = blockIdx.x * 256 + threadIdx.x;
    if (gtid < 2 * N) sums0[gtid] = 0.0f;
    if (gtid == 0) out[0] = 0.0f;
    int row = gtid >> 6;
    int l = gtid & 63;
    if (row >= N) return;
    float4 v  = ((const float4*)(C + (size_t)row * DIM))[l];
    float4 sv = ((const float4*)(S + (size_t)row * DIM))[l];
    int pc = __builtin_amdgcn_cvt_pk_fp8_f32(v.x, v.y, 0, false);
    pc     = __builtin_amdgcn_cvt_pk_fp8_f32(v.z, v.w, pc, true);
    int ps = __builtin_amdgcn_cvt_pk_fp8_f32(sv.x, sv.y, 0, false);
    ps     = __builtin_amdgcn_cvt_pk_fp8_f32(sv.z, sv.w, ps, true);
    // lane l holds bytes k = 4l..4l+3 of this row
    int idx4 = (row >> 5) * 2048 + (l >> 4) * 512 + ((l >> 2) & 1) * 256
             + ((row & 31) + 32 * ((l >> 3) & 1)) * 4 + (l & 3);
    ((int*)Cb)[idx4] = pc;
    ((int*)Sb)[idx4] = ps;
    float nc = v.x * v.x + v.y * v.y + v.z * v.z + v.w * v.w;
    float ns = sv.x * sv.x + sv.y * sv.y + sv.z * sv.z + sv.w * sv.w;
    float cr = v.x * sv.x + v.y * sv.y + v.z * sv.z + v.w * sv.w;
    #pragma unroll
    for (int off = 32; off > 0; off >>= 1) {
        nc += __shfl_down(nc, off, 64);
        ns += __shfl_down(ns, off, 64);
        cr += __shfl_down(cr, off, 64);
    }
    if (l == 0) { c2[row] = nc; s2[row] = ns; ddot[row] = cr; }
}

// ---------------------------------------------------------------------------
// Kernel 2: MX-scaled fp8 GEMM with NO LDS STAGING and NO K-loop barriers.
// R11 lesson: halving MFMA cycles didn't move the 49 us wall -> the
// barrier-paced stage/drain/ds_read structure was the limiter, not a pipe.
// Operands are loaded straight from global (operand-major layout = fragment
// layout); 16 MB total data is L2/L3-resident, and the barrier-free loop
// lets the compiler overlap loads with MFMA across K-iters. 128x128 block,
// 4 waves of 64x64 tiles (2x2 frags of 32x32). LDS: only 2 KB epilogue
// scratch. Epilogue: norms pre-scaled by K2=(e^T*log2e)^2 ->
// add+fma+max+sqrt+exp2; R11-verified zero-redundancy fold; 1 global
// atomic per row/col per block.
// C/D layout 32x32 (m74/m101): col = lane&31, row = (s&3)+8*(s>>2)+4*(l>>5).
// ---------------------------------------------------------------------------
__global__ __launch_bounds__(256, 3) void mfma_kernel(
        const unsigned char* __restrict__ Cb, const unsigned char* __restrict__ Sb,
        const float* __restrict__ c2, const float* __restrict__ s2,
        const float* __restrict__ temp,
        float* __restrict__ rowsum, float* __restrict__ colsum, int N) {
    __shared__ float rs[TM], cs[TN], c2t[TM], s2t[TN];      // 2 KB

    const int tid = threadIdx.x;
    const int bm = blockIdx.y * TM;
    const int bn = blockIdx.x * TN;
    const int w  = tid >> 6;        // 0..3
    const int l  = tid & 63;
    const int wm = (w >> 1) * 64;   // 0,64
    const int wn = (w & 1) * 64;    // 0,64

    const float escale = __expf(temp[0]);
    const float Kf = escale * 1.4426950408889634f;   // e^T * log2(e)
    const float K2 = Kf * Kf;
    const float m2K2 = -2.0f * K2;

    if (tid < TM) { rs[tid] = 0.0f; c2t[tid] = K2 * c2[bm + tid]; }
    else { int t = tid - TM; cs[t] = 0.0f; s2t[t] = K2 * s2[bn + t]; }
    __syncthreads();   // LDS init visible to all waves before epilogue

    // --- operand pointers: wave w reads A rowgroups (bm+wm)/32 + {0,1},
    // B rowgroups (bn+wn)/32 + {0,1}; fragment = 16 B at base + l*16.
    const unsigned char* baseA = Cb + (size_t)((bm + wm) >> 5) * 8192 + l * 16;
    const unsigned char* baseB = Sb + (size_t)((bn + wn) >> 5) * 8192 + l * 16;

    f32x16 acc[2][2] = {};

    #pragma unroll
    for (int kk = 0; kk < 4; ++kk) {
        v8i af[2], bf[2];
        #pragma unroll
        for (int t = 0; t < 2; ++t) {
            v4i alo = *(const v4i*)(baseA + t * 8192 + kk * 2048);
            v4i ahi = *(const v4i*)(baseA + t * 8192 + kk * 2048 + 1024);
            af[t] = __builtin_shufflevector(alo, ahi, 0, 1, 2, 3, 4, 5, 6, 7);
            v4i blo = *(const v4i*)(baseB + t * 8192 + kk * 2048);
            v4i bhi = *(const v4i*)(baseB + t * 8192 + kk * 2048 + 1024);
            bf[t] = __builtin_shufflevector(blo, bhi, 0, 1, 2, 3, 4, 5, 6, 7);
        }
        #pragma unroll
        for (int mi = 0; mi < 2; ++mi)
            #pragma unroll
            for (int ni = 0; ni < 2; ++ni)
                acc[mi][ni] = __builtin_amdgcn_mfma_scale_f32_32x32x64_f8f6f4(
                    af[mi], bf[ni], acc[mi][ni], 0, 0,   // fmt: fp8 e4m3 / e4m3
                    0, 0x7F, 0, 0x7F);                   // scales = 2^0 = 1.0
    }

    // --- fused epilogue (R11-verified fold) ---
    const int q2 = l >> 5;
    const int col5 = l & 31;
    float s2v[2] = { s2t[wn + col5], s2t[wn + 32 + col5] };

    float rfold[2];
    float cp[2] = {0.f, 0.f};

    #pragma unroll
    for (int mi = 0; mi < 2; ++mi) {
        float c2r[16];
        #pragma unroll
        for (int s = 0; s < 16; ++s)
            c2r[s] = c2t[wm + mi * 32 + (s & 3) + 8 * (s >> 2) + 4 * q2];
        float rp[16];
        #pragma unroll
        for (int s = 0; s < 16; ++s) rp[s] = 0.0f;
        #pragma unroll
        for (int ni = 0; ni < 2; ++ni) {
            #pragma unroll
            for (int s = 0; s < 16; ++s) {
                // exp2(-sqrt(K2*d2)) == exp(-escale*dist)
                float d2 = fmaf(m2K2, acc[mi][ni][s], c2r[s] + s2v[ni]);
                d2 = fmaxf(d2, 0.0f);
                float e = __builtin_amdgcn_exp2f(-__builtin_amdgcn_sqrtf(d2));
                rp[s] += e;
                cp[ni] += e;
            }
        }
        // 4-stage split-exchange fold (16 slots -> 1 over masks 1,2,4,8)
        #pragma unroll
        for (int b = 0; b < 4; ++b) {
            const int n = 16 >> b;
            const int bit = (l >> b) & 1;
            #pragma unroll
            for (int k = 0; k < 8; ++k) {
                if (k < (n >> 1)) {
                    float keep = bit ? rp[2 * k + 1] : rp[2 * k];
                    float send = bit ? rp[2 * k] : rp[2 * k + 1];
                    rp[k] = keep + __shfl_xor(send, 1 << b, 64);
                }
            }
        }
        rfold[mi] = rp[0];
    }
    // stage 5: fold lanes l <-> l^16 while splitting mi (keeps own mi)
    const int mymi = (l >> 4) & 1;
    {
        float keep = mymi ? rfold[1] : rfold[0];
        float send = mymi ? rfold[0] : rfold[1];
        float rfin = keep + __shfl_xor(send, 16, 64);
        const int s = l & 15;
        const int myrow = wm + mymi * 32 + (s & 3) + 8 * (s >> 2) + 4 * q2;
        atomicAdd(&rs[myrow], rfin);   // 2-way collision (wn pair)
    }
    // cols: fold lanes l <-> l^32 while splitting ni (keeps ni = q2)
    {
        float keep = q2 ? cp[1] : cp[0];
        float send = q2 ? cp[0] : cp[1];
        float cfin = keep + __shfl_xor(send, 32, 64);
        atomicAdd(&cs[wn + q2 * 32 + col5], cfin);   // 2-way (wm pair)
    }

    __syncthreads();
    if (tid < TM) atomicAdd(&rowsum[bm + tid], rs[tid]);
    else atomicAdd(&colsum[bn + tid - TM], cs[tid - TM]);
}

// ---------------------------------------------------------------------------
// Kernel 3: finalize, 32 blocks, atomicAdd into out[0] (zeroed by kernel 1).
// diag dist reconstructed exactly from c2/s2/ddot (fp32).
// loss = (1/2N) * sum_i [log(rowsum_i) + log(colsum_i) + 2*e^T*dist_i]
// ---------------------------------------------------------------------------
__global__ __launch_bounds__(256) void finalize_kernel(
        const float* __restrict__ rowsum, const float* __restrict__ colsum,
        const float* __restrict__ c2, const float* __restrict__ s2,
        const float* __restrict__ ddot, const float* __restrict__ temp,
        float* __restrict__ out, int N) {
    __shared__ float red[4];
    const float escale = __expf(temp[0]);
    const int tid = threadIdx.x;
    int i = blockIdx.x * 256 + tid;
    float sum = 0.0f;
    if (i < N) {
        float d2 = c2[i] + s2[i] - 2.0f * ddot[i];
        float dist = __builtin_amdgcn_sqrtf(fmaxf(d2, 0.0f));
        sum = __logf(rowsum[i]) + __logf(colsum[i]) + 2.0f * escale * dist;
    }
    #pragma unroll
    for (int off = 32; off > 0; off >>= 1) sum += __shfl_down(sum, off, 64);
    if ((tid & 63) == 0) red[tid >> 6] = sum;
    __syncthreads();
    if (tid == 0)
        atomicAdd(out, (red[0] + red[1] + red[2] + red[3]) / (2.0f * (float)N));
}

extern "C" void kernel_launch(void* const* d_in, const int* in_sizes, int n_in,
                              void* d_out, int out_size, void* d_ws, size_t ws_size,
                              hipStream_t stream) {
    const float* C = (const float*)d_in[0];
    const float* S = (const float*)d_in[1];
    const float* T = (const float*)d_in[2];
    const int N = in_sizes[0] / DIM;   // 8192

    float* ws     = (float*)d_ws;
    float* c2     = ws;
    float* s2     = ws + N;
    float* rowsum = ws + 2 * N;
    float* colsum = ws + 3 * N;
    float* ddot   = ws + 4 * N;
    unsigned char* Cb = (unsigned char*)(ws + 5 * N + 64);  // 16B-aligned
    unsigned char* Sb = Cb + (size_t)N * DIM;

    convert_kernel<<<(N * 64) / 256, 256, 0, stream>>>(
        C, S, Cb, Sb, c2, s2, ddot, rowsum, (float*)d_out, N);

    dim3 grid(N / TN, N / TM);
    mfma_kernel<<<grid, 256, 0, stream>>>(
        Cb, Sb, c2, s2, T, rowsum, colsum, N);

    finalize_kernel<<<(N + 255) / 256, 256, 0, stream>>>(
        rowsum, colsum, c2, s2, ddot, T, (float*)d_out, N);
}

// Round 13
// 104.573 us; speedup vs baseline: 1.0975x; 1.0102x over previous
//
#include <hip/hip_runtime.h>
#include <math.h>

#define DIM 256
#define TM 128          // block tile rows (cond)
#define TN 128          // block tile cols (sol)

typedef int   v4i    __attribute__((ext_vector_type(4)));
typedef int   v8i    __attribute__((ext_vector_type(8)));
typedef float f32x16 __attribute__((ext_vector_type(16)));

// ---------------------------------------------------------------------------
// Kernel 1: fp32 -> fp8 e4m3 in OPERAND-MAJOR order + exact fp32 row norms +
// exact fp32 diag cross-dots + zero-init of rowsum/colsum and out[0].
// Operand-major (R11/R12-verified): per (32-row group, 64-K group) 2048-B
// tile, byte (row,k) at i*1024 + lane*16 + j, lane=(row&31)+32*((k>>5)&1),
// i=(k>>4)&1, j=k&15. A wave's mfma_scale_32x32x64 fragment is the
// CONTIGUOUS 16 B at tile_base + lane*16 (+1024 upper half): loadable from
// global with one coalesced dwordx4 -- no LDS staging anywhere.
// ---------------------------------------------------------------------------
__global__ __launch_bounds__(256) void convert_kernel(
        const float* __restrict__ C, const float* __restrict__ S,
        unsigned char* __restrict__ Cb, unsigned char* __restrict__ Sb,
        float* __restrict__ c2, float* __restrict__ s2,
        float* __restrict__ ddot, float* __restrict__ sums0,
        float* __restrict__ out, int N) {
    int gtid = blockIdx.x * 256 + threadIdx.x;
    if (gtid < 2 * N) sums0[gtid] = 0.0f;
    if (gtid == 0) out[0] = 0.0f;
    int row = gtid >> 6;
    int l = gtid & 63;
    if (row >= N) return;
    float4 v  = ((const float4*)(C + (size_t)row * DIM))[l];
    float4 sv = ((const float4*)(S + (size_t)row * DIM))[l];
    int pc = __builtin_amdgcn_cvt_pk_fp8_f32(v.x, v.y, 0, false);
    pc     = __builtin_amdgcn_cvt_pk_fp8_f32(v.z, v.w, pc, true);
    int ps = __builtin_amdgcn_cvt_pk_fp8_f32(sv.x, sv.y, 0, false);
    ps     = __builtin_amdgcn_cvt_pk_fp8_f32(sv.z, sv.w, ps, true);
    // lane l holds bytes k = 4l..4l+3 of this row
    int idx4 = (row >> 5) * 2048 + (l >> 4) * 512 + ((l >> 2) & 1) * 256
             + ((row & 31) + 32 * ((l >> 3) & 1)) * 4 + (l & 3);
    ((int*)Cb)[idx4] = pc;
    ((int*)Sb)[idx4] = ps;
    float nc = v.x * v.x + v.y * v.y + v.z * v.z + v.w * v.w;
    float ns = sv.x * sv.x + sv.y * sv.y + sv.z * sv.z + sv.w * sv.w;
    float cr = v.x * sv.x + v.y * sv.y + v.z * sv.z + v.w * sv.w;
    #pragma unroll
    for (int off = 32; off > 0; off >>= 1) {
        nc += __shfl_down(nc, off, 64);
        ns += __shfl_down(ns, off, 64);
        cr += __shfl_down(cr, off, 64);
    }
    if (l == 0) { c2[row] = nc; s2[row] = ns; ddot[row] = cr; }
}

// ---------------------------------------------------------------------------
// Kernel 2: MX-scaled fp8 GEMM, no LDS staging, no K-loop barriers (R12),
// now with an EXPLICIT 2-deep register pipeline: kk fully unrolled
// ping-pong (load0,load1,mfma0,load2,mfma1,load3,mfma2,mfma3) so ~16
// dwordx4 loads are always in flight over each MFMA burst -- attacks the
// exposed ~200cyc L2-hit latency that R12 still paid per kk. 64 operand
// VGPRs + 64 acc + misc fits __launch_bounds__(256,3) without spills.
// Startup __syncthreads removed (LDS init only needs visibility before the
// epilogue; barrier sits after the K-loop).
// C/D layout 32x32 (m74/m101): col = lane&31, row = (s&3)+8*(s>>2)+4*(l>>5).
// ---------------------------------------------------------------------------
__global__ __launch_bounds__(256, 3) void mfma_kernel(
        const unsigned char* __restrict__ Cb, const unsigned char* __restrict__ Sb,
        const float* __restrict__ c2, const float* __restrict__ s2,
        const float* __restrict__ temp,
        float* __restrict__ rowsum, float* __restrict__ colsum, int N) {
    __shared__ float rs[TM], cs[TN], c2t[TM], s2t[TN];      // 2 KB

    const int tid = threadIdx.x;
    const int bm = blockIdx.y * TM;
    const int bn = blockIdx.x * TN;
    const int w  = tid >> 6;        // 0..3
    const int l  = tid & 63;
    const int wm = (w >> 1) * 64;   // 0,64
    const int wn = (w & 1) * 64;    // 0,64

    const float escale = __expf(temp[0]);
    const float Kf = escale * 1.4426950408889634f;   // e^T * log2(e)
    const float K2 = Kf * Kf;
    const float m2K2 = -2.0f * K2;

    if (tid < TM) { rs[tid] = 0.0f; c2t[tid] = K2 * c2[bm + tid]; }
    else { int t = tid - TM; cs[t] = 0.0f; s2t[t] = K2 * s2[bn + t]; }
    // no barrier here: K-loop doesn't touch LDS; barrier before epilogue.

    // --- operand pointers: wave w reads A rowgroups (bm+wm)/32 + {0,1},
    // B rowgroups (bn+wn)/32 + {0,1}; fragment = 16 B at base + l*16.
    const unsigned char* baseA = Cb + (size_t)((bm + wm) >> 5) * 8192 + l * 16;
    const unsigned char* baseB = Sb + (size_t)((bn + wn) >> 5) * 8192 + l * 16;

    f32x16 acc[2][2] = {};

    auto ldfrag = [&](int kk, v8i af[2], v8i bf[2]) {
        #pragma unroll
        for (int t = 0; t < 2; ++t) {
            v4i alo = *(const v4i*)(baseA + t * 8192 + kk * 2048);
            v4i ahi = *(const v4i*)(baseA + t * 8192 + kk * 2048 + 1024);
            af[t] = __builtin_shufflevector(alo, ahi, 0, 1, 2, 3, 4, 5, 6, 7);
            v4i blo = *(const v4i*)(baseB + t * 8192 + kk * 2048);
            v4i bhi = *(const v4i*)(baseB + t * 8192 + kk * 2048 + 1024);
            bf[t] = __builtin_shufflevector(blo, bhi, 0, 1, 2, 3, 4, 5, 6, 7);
        }
    };
    auto domfma = [&](v8i af[2], v8i bf[2]) {
        #pragma unroll
        for (int mi = 0; mi < 2; ++mi)
            #pragma unroll
            for (int ni = 0; ni < 2; ++ni)
                acc[mi][ni] = __builtin_amdgcn_mfma_scale_f32_32x32x64_f8f6f4(
                    af[mi], bf[ni], acc[mi][ni], 0, 0,   // fmt: fp8 e4m3
                    0, 0x7F, 0, 0x7F);                   // scales = 2^0 = 1.0
    };

    v8i a0[2], b0[2], a1[2], b1[2];
    ldfrag(0, a0, b0);
    ldfrag(1, a1, b1);
    domfma(a0, b0);
    ldfrag(2, a0, b0);
    domfma(a1, b1);
    ldfrag(3, a1, b1);
    domfma(a0, b0);
    domfma(a1, b1);

    __syncthreads();   // rs/cs/c2t/s2t init visible before epilogue use

    // --- fused epilogue (R11-verified fold) ---
    const int q2 = l >> 5;
    const int col5 = l & 31;
    float s2v[2] = { s2t[wn + col5], s2t[wn + 32 + col5] };

    float rfold[2];
    float cp[2] = {0.f, 0.f};

    #pragma unroll
    for (int mi = 0; mi < 2; ++mi) {
        float c2r[16];
        #pragma unroll
        for (int s = 0; s < 16; ++s)
            c2r[s] = c2t[wm + mi * 32 + (s & 3) + 8 * (s >> 2) + 4 * q2];
        float rp[16];
        #pragma unroll
        for (int s = 0; s < 16; ++s) rp[s] = 0.0f;
        #pragma unroll
        for (int ni = 0; ni < 2; ++ni) {
            #pragma unroll
            for (int s = 0; s < 16; ++s) {
                // exp2(-sqrt(K2*d2)) == exp(-escale*dist)
                float d2 = fmaf(m2K2, acc[mi][ni][s], c2r[s] + s2v[ni]);
                d2 = fmaxf(d2, 0.0f);
                float e = __builtin_amdgcn_exp2f(-__builtin_amdgcn_sqrtf(d2));
                rp[s] += e;
                cp[ni] += e;
            }
        }
        // 4-stage split-exchange fold (16 slots -> 1 over masks 1,2,4,8)
        #pragma unroll
        for (int b = 0; b < 4; ++b) {
            const int n = 16 >> b;
            const int bit = (l >> b) & 1;
            #pragma unroll
            for (int k = 0; k < 8; ++k) {
                if (k < (n >> 1)) {
                    float keep = bit ? rp[2 * k + 1] : rp[2 * k];
                    float send = bit ? rp[2 * k] : rp[2 * k + 1];
                    rp[k] = keep + __shfl_xor(send, 1 << b, 64);
                }
            }
        }
        rfold[mi] = rp[0];
    }
    // stage 5: fold lanes l <-> l^16 while splitting mi (keeps own mi)
    const int mymi = (l >> 4) & 1;
    {
        float keep = mymi ? rfold[1] : rfold[0];
        float send = mymi ? rfold[0] : rfold[1];
        float rfin = keep + __shfl_xor(send, 16, 64);
        const int s = l & 15;
        const int myrow = wm + mymi * 32 + (s & 3) + 8 * (s >> 2) + 4 * q2;
        atomicAdd(&rs[myrow], rfin);   // 2-way collision (wn pair)
    }
    // cols: fold lanes l <-> l^32 while splitting ni (keeps ni = q2)
    {
        float keep = q2 ? cp[1] : cp[0];
        float send = q2 ? cp[0] : cp[1];
        float cfin = keep + __shfl_xor(send, 32, 64);
        atomicAdd(&cs[wn + q2 * 32 + col5], cfin);   // 2-way (wm pair)
    }

    __syncthreads();
    if (tid < TM) atomicAdd(&rowsum[bm + tid], rs[tid]);
    else atomicAdd(&colsum[bn + tid - TM], cs[tid - TM]);
}

// ---------------------------------------------------------------------------
// Kernel 3: finalize, 32 blocks, atomicAdd into out[0] (zeroed by kernel 1).
// diag dist reconstructed exactly from c2/s2/ddot (fp32).
// loss = (1/2N) * sum_i [log(rowsum_i) + log(colsum_i) + 2*e^T*dist_i]
// ---------------------------------------------------------------------------
__global__ __launch_bounds__(256) void finalize_kernel(
        const float* __restrict__ rowsum, const float* __restrict__ colsum,
        const float* __restrict__ c2, const float* __restrict__ s2,
        const float* __restrict__ ddot, const float* __restrict__ temp,
        float* __restrict__ out, int N) {
    __shared__ float red[4];
    const float escale = __expf(temp[0]);
    const int tid = threadIdx.x;
    int i = blockIdx.x * 256 + tid;
    float sum = 0.0f;
    if (i < N) {
        float d2 = c2[i] + s2[i] - 2.0f * ddot[i];
        float dist = __builtin_amdgcn_sqrtf(fmaxf(d2, 0.0f));
        sum = __logf(rowsum[i]) + __logf(colsum[i]) + 2.0f * escale * dist;
    }
    #pragma unroll
    for (int off = 32; off > 0; off >>= 1) sum += __shfl_down(sum, off, 64);
    if ((tid & 63) == 0) red[tid >> 6] = sum;
    __syncthreads();
    if (tid == 0)
        atomicAdd(out, (red[0] + red[1] + red[2] + red[3]) / (2.0f * (float)N));
}

extern "C" void kernel_launch(void* const* d_in, const int* in_sizes, int n_in,
                              void* d_out, int out_size, void* d_ws, size_t ws_size,
                              hipStream_t stream) {
    const float* C = (const float*)d_in[0];
    const float* S = (const float*)d_in[1];
    const float* T = (const float*)d_in[2];
    const int N = in_sizes[0] / DIM;   // 8192

    float* ws     = (float*)d_ws;
    float* c2     = ws;
    float* s2     = ws + N;
    float* rowsum = ws + 2 * N;
    float* colsum = ws + 3 * N;
    float* ddot   = ws + 4 * N;
    unsigned char* Cb = (unsigned char*)(ws + 5 * N + 64);  // 16B-aligned
    unsigned char* Sb = Cb + (size_t)N * DIM;

    convert_kernel<<<(N * 64) / 256, 256, 0, stream>>>(
        C, S, Cb, Sb, c2, s2, ddot, rowsum, (float*)d_out, N);

    dim3 grid(N / TN, N / TM);
    mfma_kernel<<<grid, 256, 0, stream>>>(
        Cb, Sb, c2, s2, T, rowsum, colsum, N);

    finalize_kernel<<<(N + 255) / 256, 256, 0, stream>>>(
        rowsum, colsum, c2, s2, ddot, T, (float*)d_out, N);
}